// Round 14
// baseline (665.277 us; speedup 1.0000x reference)
//
#include <hip/hip_runtime.h>
#include <hip/hip_bf16.h>

// adLIF FUSED v7: GEMM (r6 fp32 FMA k-order -> bit-exact) + in-LDS transposed
// scan, Wx never touches HBM. v6 (r23): FETCH 274->89 MB via XCD swizzle but
// dispatch unchanged 474 -> kernel is NOT HBM-bound; Occupancy 18.5% showed the
// GRID (512 blocks = 2/CU = 8 waves/CU, 25% cap) was the limiter while VGPR 124
// permits 16 waves/CU. v7: 1024 blocks of (b, 64-h strip), 4 blocks/CU.
//   Tile 128m x 64n: acc 8x4 (32 VGPR), 3 ds_read/k, B staging halved
//   (LSTRB=68, 68%32==4 conflict-free like LSTR=132). Same total FMA (floor
//   218 us); 4 blocks/CU interleave so staging-barrier drains overlap compute.
//   LDS pipe check: 1.5 B/FMA = 393k cyc/CU < FMA 524k -> still FMA-binding.
// CLOSED ARCS: dbuf GEMM (3x condemned, VGPR>128 occupancy cliff); launch_
//   bounds min-waves (spill disaster r20/r21); NT scalar stores (5x write amp);
//   standalone scan kernel (latency floor ~140 us); HBM-fetch tuning (r23:
//   not the regime). RULE: VGPR <= 128 always.
// Swizzle: 8 strips of b -> ids {c,c+8,..,c+56} = one XCD (id%8 round-robin);
//   b=(id>>6)*8+(id&7), strip=(id>>3)&7, bijective over 1024; b's 1 MB of X
//   shared in one 4 MB L2 (r23 verified mechanism, FETCH 89 MB).
// Input dtype (fp32 vs bf16) detected on device from x's bit pattern.

#define M_SZ 65536  // B*T
#define H_SZ 512
#define K_SZ 512
#define B_SZ 128
#define T_SZ 512
#define LSTR 132   // A-tile row stride (dwords), %32==4: conflict-free staging
#define LSTRB 68   // B-tile row stride (dwords), %32==4: same property

typedef __attribute__((ext_vector_type(4))) float f32x4;

__device__ __forceinline__ bool detect_bf16(const unsigned int* __restrict__ w) {
  int c = 0;
#pragma unroll
  for (int i = 0; i < 64; ++i) {
    unsigned int e = (w[i] >> 7) & 0xffu;
    c += (e >= 115u && e <= 131u) ? 1 : 0;
  }
  return c > 32;  // bf16 exponents cluster in [115,131]; fp32 mantissa bits don't
}

template <bool ISB>
__device__ __forceinline__ f32x4 ld4t(const void* __restrict__ p, size_t off) {
  if constexpr (!ISB) {
    return *reinterpret_cast<const f32x4*>(reinterpret_cast<const float*>(p) + off);
  } else {
    uint2 v = *reinterpret_cast<const uint2*>(reinterpret_cast<const unsigned short*>(p) + off);
    f32x4 r;
    r.x = __uint_as_float((v.x & 0xffffu) << 16);
    r.y = __uint_as_float(v.x & 0xffff0000u);
    r.z = __uint_as_float((v.y & 0xffffu) << 16);
    r.w = __uint_as_float(v.y & 0xffff0000u);
    return r;
  }
}

template <bool ISB>
__device__ __forceinline__ float ld1t(const void* __restrict__ p, int i) {
  if constexpr (!ISB) return reinterpret_cast<const float*>(p)[i];
  return __uint_as_float((unsigned int)(reinterpret_cast<const unsigned short*>(p)[i]) << 16);
}

// ---------------- fused GEMM + scan body ------------------------------------
template <bool ISB>
__device__ __forceinline__ void fused_body(
    const void* __restrict__ X, const void* __restrict__ Wm,
    const void* __restrict__ alpha_p, const void* __restrict__ beta_p,
    const void* __restrict__ a_p, const void* __restrict__ b_p,
    const void* __restrict__ u0p, const void* __restrict__ w0p,
    const void* __restrict__ s0p, void* __restrict__ out,
    float* __restrict__ As, float* __restrict__ Bs, float* __restrict__ wxs) {
  const int tid = threadIdx.x;
  const int r0 = tid >> 2;       // 0..63: staged row
  const int q0 = (tid & 3) * 4;  // 0,4,8,12: k-group
  const int tx = tid & 15;       // n-group (16 x 4 = 64 n)
  const int ty = tid >> 4;       // m-group (16 x 8 = 128 m)
  // XCD swizzle: 8 strips of batch b -> one XCD. Bijective over 1024.
  const int id = blockIdx.x;
  const int b = ((id >> 6) << 3) + (id & 7);
  const int N0 = ((id >> 3) & 7) * 64;

  // ---- scan state: REGISTERS, thread tid<64 owns column n=tid (h=N0+tid)
  float al = 0.f, be = 0.f, av = 0.f, bv = 0.f, om = 0.f, u = 0.f, w = 0.f, s = 0.f;
  if (tid < 64) {
    const int h = N0 + tid;
    al = fminf(fmaxf(ld1t<ISB>(alpha_p, h), (float)0.8187307530779818),
               (float)0.9607894391523232);
    be = fminf(fmaxf(ld1t<ISB>(beta_p, h), (float)0.9672161004820059),
               (float)0.9917013044213351);
    av = fminf(fmaxf(ld1t<ISB>(a_p, h), -1.0f), 1.0f);
    bv = fminf(fmaxf(ld1t<ISB>(b_p, h), 0.0f), 2.0f);
    om = __fsub_rn(1.0f, al);
    const int bh = b * H_SZ + h;
    u = ld1t<ISB>(u0p, bh);
    w = ld1t<ISB>(w0p, bh);
    s = ld1t<ISB>(s0p, bh);
  }

  float* outf = reinterpret_cast<float*>(out);
  unsigned short* outu = reinterpret_cast<unsigned short*>(out);

  const size_t boff0 = (size_t)(N0 + r0) * K_SZ + q0;  // W rows N0..N0+63

  for (int tt = 0; tt < 4; ++tt) {  // M-tile = 128 consecutive t of batch b
    const size_t M0 = (size_t)b * T_SZ + tt * 128;

    float acc[8][4];
#pragma unroll
    for (int i = 0; i < 8; ++i)
#pragma unroll
      for (int j = 0; j < 4; ++j) acc[i][j] = 0.0f;

    const size_t aoff0 = (M0 + r0) * K_SZ + q0;
    const size_t aoff1 = (M0 + r0 + 64) * K_SZ + q0;

    f32x4 pa0 = ld4t<ISB>(X, aoff0), pa1 = ld4t<ISB>(X, aoff1);
    f32x4 pb0 = ld4t<ISB>(Wm, boff0);

    for (int kk = 0; kk < K_SZ; kk += 16) {  // r6 2-barrier k-loop
      __syncthreads();  // prior compute done -> LDS free
      As[(q0 + 0) * LSTR + r0] = pa0.x; As[(q0 + 1) * LSTR + r0] = pa0.y;
      As[(q0 + 2) * LSTR + r0] = pa0.z; As[(q0 + 3) * LSTR + r0] = pa0.w;
      As[(q0 + 0) * LSTR + r0 + 64] = pa1.x; As[(q0 + 1) * LSTR + r0 + 64] = pa1.y;
      As[(q0 + 2) * LSTR + r0 + 64] = pa1.z; As[(q0 + 3) * LSTR + r0 + 64] = pa1.w;
      Bs[(q0 + 0) * LSTRB + r0] = pb0.x; Bs[(q0 + 1) * LSTRB + r0] = pb0.y;
      Bs[(q0 + 2) * LSTRB + r0] = pb0.z; Bs[(q0 + 3) * LSTRB + r0] = pb0.w;
      __syncthreads();  // tile ready
      if (kk + 16 < K_SZ) {  // prefetch next chunk (L2-hit under swizzle)
        pa0 = ld4t<ISB>(X, aoff0 + kk + 16); pa1 = ld4t<ISB>(X, aoff1 + kk + 16);
        pb0 = ld4t<ISB>(Wm, boff0 + kk + 16);
      }
#pragma unroll
      for (int k = 0; k < 16; ++k) {
        const f32x4 a0 = *reinterpret_cast<const f32x4*>(As + k * LSTR + ty * 4);
        const f32x4 a1 = *reinterpret_cast<const f32x4*>(As + k * LSTR + 64 + ty * 4);
        const f32x4 b0 = *reinterpret_cast<const f32x4*>(Bs + k * LSTRB + tx * 4);
        const float avv[8] = {a0.x, a0.y, a0.z, a0.w, a1.x, a1.y, a1.z, a1.w};
        const float bvv[4] = {b0.x, b0.y, b0.z, b0.w};
#pragma unroll
        for (int i = 0; i < 8; ++i)
#pragma unroll
          for (int j = 0; j < 4; ++j) acc[i][j] += avv[i] * bvv[j];  // contracts to FMA
      }
    }
    // acc[r][j] = Wx[t_local = (r<4 ? ty*4+r : 64+ty*4+(r-4))][n = tx*4+j].
    // Scan in 4 subs of 32 t: sub0 ty<8 rows 0..3; sub1 ty>=8 rows 0..3;
    //                         sub2 ty<8 rows 4..7; sub3 ty>=8 rows 4..7.
#pragma unroll
    for (int sub = 0; sub < 4; ++sub) {
      __syncthreads();  // prior sub's wxs reads (or k-loop compute) complete
      const bool owner = (sub & 1) ? (ty >= 8) : (ty < 8);  // wave-uniform
      if (owner) {
#pragma unroll
        for (int rr = 0; rr < 4; ++rr) {
          const int row = (ty & 7) * 4 + rr;          // t within sub
          const int r = (sub < 2) ? rr : 4 + rr;      // static acc row
          f32x4 v0 = {acc[r][0], acc[r][1], acc[r][2], acc[r][3]};
          *reinterpret_cast<f32x4*>(wxs + row * 64 + tx * 4) = v0;
        }
      }
      __syncthreads();  // wxs[32][64] ready
      if (tid < 64) {  // wave-uniform: wave 0 scans, one column per thread
        const size_t tbase =
            ((size_t)b * T_SZ + tt * 128 + sub * 32) * H_SZ + N0 + tid;
#pragma unroll
        for (int t = 0; t < 32; ++t) {
          const float cur = wxs[t * 64 + tid];  // independent of recurrence
          // numpy left-to-right, each op individually rounded (no FMA contraction)
          w = __fadd_rn(__fadd_rn(__fmul_rn(be, w), __fmul_rn(av, u)), __fmul_rn(bv, s));
          u = __fadd_rn(__fmul_rn(al, __fsub_rn(u, s)), __fmul_rn(om, __fsub_rn(cur, w)));
          const bool sp = (u > 1.0f);
          s = sp ? 1.0f : 0.0f;
          // plain stores: 64 lanes x 4B contiguous = 256 B, L2 write-combined
          if constexpr (ISB)
            outu[tbase + (size_t)t * H_SZ] = sp ? (unsigned short)0x3F80u : (unsigned short)0u;
          else
            outf[tbase + (size_t)t * H_SZ] = s;
        }
      }
    }
  }
}

__global__ __launch_bounds__(256) void adlif_fused(
    const void* __restrict__ X, const void* __restrict__ Wm,
    const void* __restrict__ alpha_p, const void* __restrict__ beta_p,
    const void* __restrict__ a_p, const void* __restrict__ b_p,
    const void* __restrict__ u0p, const void* __restrict__ w0p,
    const void* __restrict__ s0p, void* __restrict__ out) {
  __shared__ float As[16 * LSTR];   // 8.45 KB A-tile staging (128 m x 16 k)
  __shared__ float Bs[16 * LSTRB];  // 4.35 KB B-tile staging (64 n x 16 k)
  __shared__ float wxs[32 * 64];    // 8 KB Wx transpose buffer (one 32-t sub)
  if (detect_bf16(reinterpret_cast<const unsigned int*>(X)))
    fused_body<true>(X, Wm, alpha_p, beta_p, a_p, b_p, u0p, w0p, s0p, out, As, Bs, wxs);
  else
    fused_body<false>(X, Wm, alpha_p, beta_p, a_p, b_p, u0p, w0p, s0p, out, As, Bs, wxs);
}

extern "C" void kernel_launch(void* const* d_in, const int* in_sizes, int n_in,
                              void* d_out, int out_size, void* d_ws, size_t ws_size,
                              hipStream_t stream) {
  // single fused dispatch; d_ws unused (Wx never materialized in HBM)
  adlif_fused<<<dim3(B_SZ * 8), dim3(256), 0, stream>>>(
      d_in[0], d_in[1], d_in[2], d_in[3], d_in[4], d_in[5], d_in[6], d_in[7],
      d_in[8], d_out);
}

// Round 15
// 620.121 us; speedup vs baseline: 1.0728x; 1.0728x over previous
//
#include <hip/hip_runtime.h>
#include <hip/hip_bf16.h>

// adLIF FUSED v8: GEMM (fp32 FMA, k ascending -> bit-exact) + in-LDS transposed
// scan, Wx never touches HBM. CLEAN OCCUPANCY TEST:
//   r23 (best fused: dispatch 474/bench 593): 256 thr, tile 128x128, 8 waves/CU
//     (25% cap, grid-limited), VALUBusy 61%, FMA floor 218 us.
//   r24 FAILED CONFOUNDED: 128x64 tile cut intensity 16->10.7 MAC/B, +1.5x
//     staging instrs, +1.5x bank conflicts -> 549 us. Not an occupancy test.
//   v8: 512 threads/block, tile STAYS 128x128, grid STAYS 512 (r23 swizzle
//     verbatim, FETCH 89 MB banked). Identical staging instr total, LDS tiles,
//     barriers, intensity; acc halves to 4x8/thread (32 VGPR); each thread
//     stages ONE A + ONE B f32x4 (r0 = tid>>2 spans 128 rows). Only delta:
//     16 waves/CU resident (50% cap) vs 8. Falsifier: dispatch >= 474 or
//     occupancy <= 22% -> occupancy arc closes, revert r23, declare plateau.
// CLOSED ARCS: dbuf GEMM (3x, VGPR>128 cliff); launch_bounds min-waves (spill
//   disaster); NT scalar stores (5x write amp); standalone scan (latency floor
//   ~140 us); HBM-fetch tuning (not the regime); small tiles (r24 intensity).
// Input dtype (fp32 vs bf16) detected on device from x's bit pattern.

#define M_SZ 65536  // B*T
#define H_SZ 512
#define K_SZ 512
#define B_SZ 128
#define T_SZ 512
#define LSTR 132  // LDS row stride (dwords), %32==4: 2-way-max staging (free)

typedef __attribute__((ext_vector_type(4))) float f32x4;

__device__ __forceinline__ bool detect_bf16(const unsigned int* __restrict__ w) {
  int c = 0;
#pragma unroll
  for (int i = 0; i < 64; ++i) {
    unsigned int e = (w[i] >> 7) & 0xffu;
    c += (e >= 115u && e <= 131u) ? 1 : 0;
  }
  return c > 32;  // bf16 exponents cluster in [115,131]; fp32 mantissa bits don't
}

template <bool ISB>
__device__ __forceinline__ f32x4 ld4t(const void* __restrict__ p, size_t off) {
  if constexpr (!ISB) {
    return *reinterpret_cast<const f32x4*>(reinterpret_cast<const float*>(p) + off);
  } else {
    uint2 v = *reinterpret_cast<const uint2*>(reinterpret_cast<const unsigned short*>(p) + off);
    f32x4 r;
    r.x = __uint_as_float((v.x & 0xffffu) << 16);
    r.y = __uint_as_float(v.x & 0xffff0000u);
    r.z = __uint_as_float((v.y & 0xffffu) << 16);
    r.w = __uint_as_float(v.y & 0xffff0000u);
    return r;
  }
}

template <bool ISB>
__device__ __forceinline__ float ld1t(const void* __restrict__ p, int i) {
  if constexpr (!ISB) return reinterpret_cast<const float*>(p)[i];
  return __uint_as_float((unsigned int)(reinterpret_cast<const unsigned short*>(p)[i]) << 16);
}

// ---------------- fused GEMM + scan body ------------------------------------
template <bool ISB>
__device__ __forceinline__ void fused_body(
    const void* __restrict__ X, const void* __restrict__ Wm,
    const void* __restrict__ alpha_p, const void* __restrict__ beta_p,
    const void* __restrict__ a_p, const void* __restrict__ b_p,
    const void* __restrict__ u0p, const void* __restrict__ w0p,
    const void* __restrict__ s0p, void* __restrict__ out,
    float* __restrict__ As, float* __restrict__ Bs, float* __restrict__ wxs) {
  const int tid = threadIdx.x;           // 0..511
  const int r0 = tid >> 2;               // 0..127: staged row (A and B)
  const int q0 = (tid & 3) * 4;          // 0,4,8,12: k-group
  const int tx = tid & 15;               // n-group (16 x 8 = 128 n)
  const int ty = tid >> 4;               // m-group (32 x 4 = 128 m)
  // XCD swizzle (r23 verbatim, FETCH 89 MB verified): 4 strips of b -> one XCD.
  const int id = blockIdx.x;
  const int b = ((id >> 5) << 3) + (id & 7);
  const int N0 = ((id >> 3) & 3) * 128;

  // ---- scan state: REGISTERS, thread tid<128 owns column n=tid (h=N0+tid)
  float al = 0.f, be = 0.f, av = 0.f, bv = 0.f, om = 0.f, u = 0.f, w = 0.f, s = 0.f;
  if (tid < 128) {
    const int h = N0 + tid;
    al = fminf(fmaxf(ld1t<ISB>(alpha_p, h), (float)0.8187307530779818),
               (float)0.9607894391523232);
    be = fminf(fmaxf(ld1t<ISB>(beta_p, h), (float)0.9672161004820059),
               (float)0.9917013044213351);
    av = fminf(fmaxf(ld1t<ISB>(a_p, h), -1.0f), 1.0f);
    bv = fminf(fmaxf(ld1t<ISB>(b_p, h), 0.0f), 2.0f);
    om = __fsub_rn(1.0f, al);
    const int bh = b * H_SZ + h;
    u = ld1t<ISB>(u0p, bh);
    w = ld1t<ISB>(w0p, bh);
    s = ld1t<ISB>(s0p, bh);
  }

  float* outf = reinterpret_cast<float*>(out);
  unsigned short* outu = reinterpret_cast<unsigned short*>(out);

  const size_t boff = (size_t)(N0 + r0) * K_SZ + q0;  // W row N0+r0

  for (int tt = 0; tt < 4; ++tt) {  // M-tile = 128 consecutive t of batch b
    const size_t M0 = (size_t)b * T_SZ + tt * 128;

    float acc[4][8];
#pragma unroll
    for (int i = 0; i < 4; ++i)
#pragma unroll
      for (int j = 0; j < 8; ++j) acc[i][j] = 0.0f;

    const size_t aoff = (M0 + r0) * K_SZ + q0;  // X row M0+r0

    f32x4 pa = ld4t<ISB>(X, aoff);
    f32x4 pb = ld4t<ISB>(Wm, boff);

    for (int kk = 0; kk < K_SZ; kk += 16) {  // 2-barrier k-loop (proven)
      __syncthreads();  // prior compute done -> LDS free
      As[(q0 + 0) * LSTR + r0] = pa.x; As[(q0 + 1) * LSTR + r0] = pa.y;
      As[(q0 + 2) * LSTR + r0] = pa.z; As[(q0 + 3) * LSTR + r0] = pa.w;
      Bs[(q0 + 0) * LSTR + r0] = pb.x; Bs[(q0 + 1) * LSTR + r0] = pb.y;
      Bs[(q0 + 2) * LSTR + r0] = pb.z; Bs[(q0 + 3) * LSTR + r0] = pb.w;
      __syncthreads();  // tile ready
      if (kk + 16 < K_SZ) {  // prefetch next chunk (L2-hit under swizzle)
        pa = ld4t<ISB>(X, aoff + kk + 16);
        pb = ld4t<ISB>(Wm, boff + kk + 16);
      }
#pragma unroll
      for (int k = 0; k < 16; ++k) {
        const f32x4 a0 = *reinterpret_cast<const f32x4*>(As + k * LSTR + ty * 4);
        const f32x4 b0 = *reinterpret_cast<const f32x4*>(Bs + k * LSTR + tx * 4);
        const f32x4 b1 = *reinterpret_cast<const f32x4*>(Bs + k * LSTR + 64 + tx * 4);
        const float avv[4] = {a0.x, a0.y, a0.z, a0.w};
        const float bvv[8] = {b0.x, b0.y, b0.z, b0.w, b1.x, b1.y, b1.z, b1.w};
#pragma unroll
        for (int i = 0; i < 4; ++i)
#pragma unroll
          for (int j = 0; j < 8; ++j) acc[i][j] += avv[i] * bvv[j];  // contracts to FMA
      }
    }
    // acc[i][j] = Wx[t_local = ty*4+i][n = (j<4 ? tx*4+j : 64+tx*4+(j-4))].
    // Scan in 4 subs of 32 t; sub s owned by ty in [8s, 8s+8) = waves 2s,2s+1.
#pragma unroll
    for (int sub = 0; sub < 4; ++sub) {
      __syncthreads();  // prior sub's wxs reads (or k-loop compute) complete
      if ((ty >> 3) == sub) {  // wave-uniform owner
#pragma unroll
        for (int rr = 0; rr < 4; ++rr) {
          const int row = (ty & 7) * 4 + rr;  // t within sub; t_local = ty*4+rr
          f32x4 v0 = {acc[rr][0], acc[rr][1], acc[rr][2], acc[rr][3]};
          f32x4 v1 = {acc[rr][4], acc[rr][5], acc[rr][6], acc[rr][7]};
          *reinterpret_cast<f32x4*>(wxs + row * 128 + tx * 4) = v0;
          *reinterpret_cast<f32x4*>(wxs + row * 128 + 64 + tx * 4) = v1;
        }
      }
      __syncthreads();  // wxs[32][128] ready
      if (tid < 128) {  // wave-uniform: waves 0-1 scan, one column per thread
        const size_t tbase =
            ((size_t)b * T_SZ + tt * 128 + sub * 32) * H_SZ + N0 + tid;
#pragma unroll
        for (int t = 0; t < 32; ++t) {
          const float cur = wxs[t * 128 + tid];  // independent of recurrence
          // numpy left-to-right, each op individually rounded (no FMA contraction)
          w = __fadd_rn(__fadd_rn(__fmul_rn(be, w), __fmul_rn(av, u)), __fmul_rn(bv, s));
          u = __fadd_rn(__fmul_rn(al, __fsub_rn(u, s)), __fmul_rn(om, __fsub_rn(cur, w)));
          const bool sp = (u > 1.0f);
          s = sp ? 1.0f : 0.0f;
          // plain stores: 128 lanes x 4B contiguous -> L2 write-combined
          if constexpr (ISB)
            outu[tbase + (size_t)t * H_SZ] = sp ? (unsigned short)0x3F80u : (unsigned short)0u;
          else
            outf[tbase + (size_t)t * H_SZ] = s;
        }
      }
    }
  }
}

__global__ __launch_bounds__(512) void adlif_fused(
    const void* __restrict__ X, const void* __restrict__ Wm,
    const void* __restrict__ alpha_p, const void* __restrict__ beta_p,
    const void* __restrict__ a_p, const void* __restrict__ b_p,
    const void* __restrict__ u0p, const void* __restrict__ w0p,
    const void* __restrict__ s0p, void* __restrict__ out) {
  __shared__ float As[16 * LSTR];   // 8.45 KB A-tile staging (128 m x 16 k)
  __shared__ float Bs[16 * LSTR];   // 8.45 KB B-tile staging (128 n x 16 k)
  __shared__ float wxs[32 * 128];   // 16 KB Wx transpose buffer (one 32-t sub)
  if (detect_bf16(reinterpret_cast<const unsigned int*>(X)))
    fused_body<true>(X, Wm, alpha_p, beta_p, a_p, b_p, u0p, w0p, s0p, out, As, Bs, wxs);
  else
    fused_body<false>(X, Wm, alpha_p, beta_p, a_p, b_p, u0p, w0p, s0p, out, As, Bs, wxs);
}

extern "C" void kernel_launch(void* const* d_in, const int* in_sizes, int n_in,
                              void* d_out, int out_size, void* d_ws, size_t ws_size,
                              hipStream_t stream) {
  // single fused dispatch; d_ws unused (Wx never materialized in HBM)
  adlif_fused<<<dim3(B_SZ * 4), dim3(512), 0, stream>>>(
      d_in[0], d_in[1], d_in[2], d_in[3], d_in[4], d_in[5], d_in[6], d_in[7],
      d_in[8], d_out);
}